// Round 1
// baseline (395.655 us; speedup 1.0000x reference)
//
#include <hip/hip_runtime.h>
#include <math.h>

#pragma clang fp contract(off)

#define Bn 2
#define Vn 8000
#define Fn 1500
#define Hn 128
#define Wn 128
#define EPS_AREA_F 1e-8f
#define EPS_Z_F 1e-4f
#define TILE 256

// Per-face record: 3 x float4 = {x0,y0,z0,x1}, {y1,z1,x2,y2}, {z2,area,area_safe,0}
__global__ void prep_kernel(const float* __restrict__ verts, const float* __restrict__ R,
                            const float* __restrict__ T, const float* __restrict__ focal,
                            const int* __restrict__ faces, float4* __restrict__ rec) {
    int t = blockIdx.x * blockDim.x + threadIdx.x;
    if (t >= Bn * Fn) return;
    int b = t / Fn;
    int f = t - b * Fn;
    const float* Rb = R + b * 9;
    const float* Tb = T + b * 3;
    float fo = focal[0];
    float X[3], Y[3], Z[3];
    for (int k = 0; k < 3; ++k) {
        int vi = faces[f * 3 + k];
        const float* v = verts + ((size_t)b * Vn + vi) * 3;
        float v0 = v[0], v1 = v[1], v2 = v[2];
        // einsum 'bvi,bij->bvj': vv_j = v0*R[0,j] + v1*R[1,j] + v2*R[2,j], then +T
        float vx = v0 * Rb[0] + v1 * Rb[3] + v2 * Rb[6] + Tb[0];
        float vy = v0 * Rb[1] + v1 * Rb[4] + v2 * Rb[7] + Tb[1];
        float vz = v0 * Rb[2] + v1 * Rb[5] + v2 * Rb[8] + Tb[2];
        X[k] = (fo * vx) / vz;
        Y[k] = (fo * vy) / vz;
        Z[k] = vz;
    }
    // area = _edge(v0, v1, v2) = (x2-x0)*(y1-y0) - (y2-y0)*(x1-x0)
    float area = (X[2] - X[0]) * (Y[1] - Y[0]) - (Y[2] - Y[0]) * (X[1] - X[0]);
    float as = (fabsf(area) > EPS_AREA_F) ? area : EPS_AREA_F;
    rec[t * 3 + 0] = make_float4(X[0], Y[0], Z[0], X[1]);
    rec[t * 3 + 1] = make_float4(Y[1], Z[1], X[2], Y[2]);
    rec[t * 3 + 2] = make_float4(Z[2], area, as, 0.0f);
}

__global__ void raster_kernel(const float4* __restrict__ rec, float* __restrict__ out) {
    __shared__ float4 sm[TILE * 3];
    int p = blockIdx.x * blockDim.x + threadIdx.x;   // 0 .. B*H*W-1
    int b = p >> 14;            // / (H*W) = 16384
    int hw = p & 16383;
    int h = hw >> 7;            // / W
    int w = hw & 127;
    // px = 1 - 2*(w+0.5)/W  (exact in fp32: /128 is a power of two)
    float px = 1.0f - (2.0f * ((float)w + 0.5f)) / (float)Wn;
    float py = 1.0f - (2.0f * ((float)h + 0.5f)) / (float)Hn;

    const float4* rb = rec + (size_t)b * Fn * 3;

    float zmin = __builtin_inff();
    int idx = -1;
    float c0 = 0.0f, c1 = 0.0f, c2 = 0.0f;

    for (int base = 0; base < Fn; base += TILE) {
        int cnt = (Fn - base < TILE) ? (Fn - base) : TILE;
        __syncthreads();
        for (int i = threadIdx.x; i < cnt * 3; i += blockDim.x)
            sm[i] = rb[base * 3 + i];
        __syncthreads();
        for (int j = 0; j < cnt; ++j) {
            float4 r0 = sm[j * 3 + 0];
            float4 r1 = sm[j * 3 + 1];
            float4 r2 = sm[j * 3 + 2];
            float x0 = r0.x, y0 = r0.y, z0 = r0.z, x1 = r0.w;
            float y1 = r1.x, z1 = r1.y, x2 = r1.z, y2 = r1.w;
            float z2 = r2.x, area = r2.y, as = r2.z;
            // exact reference op order (_edge), contraction off
            float w0 = (px - x1) * (y2 - y1) - (py - y1) * (x2 - x1);
            float w1 = (px - x2) * (y0 - y2) - (py - y2) * (x0 - x2);
            float w2 = (px - x0) * (y1 - y0) - (py - y0) * (x1 - x0);
            float b0 = w0 / as;
            float b1 = w1 / as;
            float b2 = w2 / as;
            bool inside = (b0 >= 0.0f) & (b1 >= 0.0f) & (b2 >= 0.0f) &
                          (fabsf(area) > EPS_AREA_F);
            float zp = (b0 * z0 + b1 * z1) + b2 * z2;
            bool valid = inside && (zp > EPS_Z_F);
            if (valid && zp < zmin) {  // strict < keeps first index on ties (argmin)
                zmin = zp; idx = base + j; c0 = b0; c1 = b1; c2 = b2;
            }
        }
    }

    bool hit = (idx >= 0);
    const int HWB = Bn * Hn * Wn;  // 32768
    float o_idx = -1.0f, o_z = -1.0f, ob0 = -1.0f, ob1 = -1.0f, ob2 = -1.0f, o_d = -1.0f;
    if (hit) {
        float4 r0 = rec[(size_t)b * Fn * 3 + idx * 3 + 0];
        float4 r1 = rec[(size_t)b * Fn * 3 + idx * 3 + 1];
        float x0 = r0.x, y0 = r0.y, x1 = r0.w;
        float y1 = r1.x, x2 = r1.z, y2 = r1.w;
        auto seg = [&](float ax, float ay, float bx, float by) -> float {
            float dx = bx - ax, dy = by - ay;
            float l2 = dx * dx + dy * dy;
            l2 = (l2 > 1e-12f) ? l2 : 1e-12f;   // jnp.maximum(l2, 1e-12)
            float q = ((px - ax) * dx + (py - ay) * dy) / l2;
            q = (q < 0.0f) ? 0.0f : ((q > 1.0f) ? 1.0f : q);  // clip
            float ex = (ax + q * dx) - px;
            float ey = (ay + q * dy) - py;
            return ex * ex + ey * ey;
        };
        float d01 = seg(x0, y0, x1, y1);
        float d12 = seg(x1, y1, x2, y2);
        float d20 = seg(x2, y2, x0, y0);
        float d2 = fminf(fminf(d01, d12), d20);
        bool inside_b = (c0 >= 0.0f) && (c1 >= 0.0f) && (c2 >= 0.0f);
        o_idx = (float)idx;
        o_z = zmin;            // zbest == zp of winner, bit-identical expression
        ob0 = c0; ob1 = c1; ob2 = c2;
        o_d = inside_b ? -d2 : d2;
    }
    // outputs concatenated flat: pix_to_face | zbuf | bary(x3) | dists
    out[p] = o_idx;
    out[HWB + p] = o_z;
    out[2 * HWB + p * 3 + 0] = ob0;
    out[2 * HWB + p * 3 + 1] = ob1;
    out[2 * HWB + p * 3 + 2] = ob2;
    out[5 * HWB + p] = o_d;
}

extern "C" void kernel_launch(void* const* d_in, const int* in_sizes, int n_in,
                              void* d_out, int out_size, void* d_ws, size_t ws_size,
                              hipStream_t stream) {
    const float* verts = (const float*)d_in[0];
    const float* R     = (const float*)d_in[1];
    const float* T     = (const float*)d_in[2];
    const float* focal = (const float*)d_in[3];
    const int*   faces = (const int*)d_in[4];
    float* out = (float*)d_out;
    float4* rec = (float4*)d_ws;   // B*F*3 float4 = 144 KB

    hipLaunchKernelGGL(prep_kernel, dim3((Bn * Fn + 255) / 256), dim3(256), 0, stream,
                       verts, R, T, focal, faces, rec);
    hipLaunchKernelGGL(raster_kernel, dim3((Bn * Hn * Wn) / 64), dim3(64), 0, stream,
                       rec, out);
}

// Round 2
// 126.795 us; speedup vs baseline: 3.1204x; 3.1204x over previous
//
#include <hip/hip_runtime.h>
#include <math.h>

#pragma clang fp contract(off)

#define Bn 2
#define Vn 8000
#define Fn 1500
#define Hn 128
#define Wn 128
#define EPS_AREA_F 1e-8f
#define EPS_Z_F 1e-4f

#define NSEG 16
#define SEGF 94            // ceil(1500/16)
#define SLOT 96            // padded LDS slots per segment

// recXY: per face 2 x float4 = {x0,y0,x1,y1}, {x2,y2,area,area_safe}
// recZ : per face 1 x float4 = {z0,z1,z2,0}
__global__ void prep_kernel(const float* __restrict__ verts, const float* __restrict__ R,
                            const float* __restrict__ T, const float* __restrict__ focal,
                            const int* __restrict__ faces,
                            float4* __restrict__ recXY, float4* __restrict__ recZ) {
    int t = blockIdx.x * blockDim.x + threadIdx.x;
    if (t >= Bn * Fn) return;
    int b = t / Fn;
    int f = t - b * Fn;
    const float* Rb = R + b * 9;
    const float* Tb = T + b * 3;
    float fo = focal[0];
    float X[3], Y[3], Z[3];
    for (int k = 0; k < 3; ++k) {
        int vi = faces[f * 3 + k];
        const float* v = verts + ((size_t)b * Vn + vi) * 3;
        float v0 = v[0], v1 = v[1], v2 = v[2];
        float vx = v0 * Rb[0] + v1 * Rb[3] + v2 * Rb[6] + Tb[0];
        float vy = v0 * Rb[1] + v1 * Rb[4] + v2 * Rb[7] + Tb[1];
        float vz = v0 * Rb[2] + v1 * Rb[5] + v2 * Rb[8] + Tb[2];
        X[k] = (fo * vx) / vz;
        Y[k] = (fo * vy) / vz;
        Z[k] = vz;
    }
    float area = (X[2] - X[0]) * (Y[1] - Y[0]) - (Y[2] - Y[0]) * (X[1] - X[0]);
    float as = (fabsf(area) > EPS_AREA_F) ? area : EPS_AREA_F;
    recXY[t * 2 + 0] = make_float4(X[0], Y[0], X[1], Y[1]);
    recXY[t * 2 + 1] = make_float4(X[2], Y[2], area, as);
    recZ[t] = make_float4(Z[0], Z[1], Z[2], 0.0f);
}

__global__ __launch_bounds__(1024, 4)
void raster_kernel(const float4* __restrict__ recXY, const float4* __restrict__ recZ,
                   float* __restrict__ out) {
    __shared__ float4 smF[NSEG * SLOT * 2];              // 49152 B
    __shared__ unsigned long long smK[NSEG * 64];        // 8192 B

    int tid = threadIdx.x;
    int lane = tid & 63;
    int seg = tid >> 6;
    int blk = blockIdx.x;
    int b = blk >> 8;                 // 256 tiles per batch
    int tile = blk & 255;
    int h = ((tile >> 4) << 3) | (lane >> 3);   // 8x8 pixel tile per wave
    int w = ((tile & 15) << 3) | (lane & 7);
    float px = 1.0f - (2.0f * ((float)w + 0.5f)) / (float)Wn;
    float py = 1.0f - (2.0f * ((float)h + 0.5f)) / (float)Hn;

    int fbase = seg * SEGF;
    int cnt = Fn - fbase; if (cnt > SEGF) cnt = SEGF;

    // stage this segment's face XY records into LDS (wave-local chunk)
    float4* dst = smF + seg * SLOT * 2;
    const float4* src = recXY + ((size_t)b * Fn + fbase) * 2;
    for (int i = lane; i < cnt * 2; i += 64) dst[i] = src[i];
    __syncthreads();

    const float4* rzb = recZ + (size_t)b * Fn;

    float zmin = __builtin_inff();
    int idx = -1;
    for (int j = 0; j < cnt; ++j) {
        float4 q0 = dst[j * 2 + 0];
        float4 q1 = dst[j * 2 + 1];
        float x0 = q0.x, y0 = q0.y, x1 = q0.z, y1 = q0.w;
        float x2 = q1.x, y2 = q1.y, area = q1.z, as = q1.w;
        // exact reference op order (_edge), contraction off
        float w0 = (px - x1) * (y2 - y1) - (py - y1) * (x2 - x1);
        float w1 = (px - x2) * (y0 - y2) - (py - y2) * (x0 - x2);
        float w2 = (px - x0) * (y1 - y0) - (py - y0) * (x1 - x0);
        // sign-only inside test: w/as >= 0 iff sign(w)==sign(as) or w==+-0
        bool areaok = fabsf(area) > EPS_AREA_F;
        bool ins = areaok && ((as > 0.0f) ? (w0 >= 0.0f && w1 >= 0.0f && w2 >= 0.0f)
                                          : (w0 <= 0.0f && w1 <= 0.0f && w2 <= 0.0f));
        if (ins) {
            // exact path only for survivors
            float b0 = w0 / as;
            float b1 = w1 / as;
            float b2 = w2 / as;
            float4 qz = rzb[fbase + j];
            float zp = (b0 * qz.x + b1 * qz.y) + b2 * qz.z;
            if (zp > EPS_Z_F && zp < zmin) {   // strict < keeps first index (argmin)
                zmin = zp; idx = fbase + j;
            }
        }
    }
    unsigned long long key = (idx < 0) ? ~0ull
        : ((unsigned long long)__float_as_uint(zmin) << 32) | (unsigned)idx;
    smK[seg * 64 + lane] = key;
    __syncthreads();

    if (tid < 64) {
        unsigned long long best = smK[tid];
        #pragma unroll
        for (int s = 1; s < NSEG; ++s) {
            unsigned long long k = smK[s * 64 + tid];
            if (k < best) best = k;
        }
        const int HWB = Bn * Hn * Wn;
        int p = b * (Hn * Wn) + h * Wn + w;
        float o_idx = -1.0f, o_z = -1.0f, ob0 = -1.0f, ob1 = -1.0f, ob2 = -1.0f, o_d = -1.0f;
        if (best != ~0ull) {
            int f = (int)(best & 0xFFFFFFFFu);
            int s = f / SEGF, sl = f - s * SEGF;
            float4 q0 = smF[(s * SLOT + sl) * 2 + 0];
            float4 q1 = smF[(s * SLOT + sl) * 2 + 1];
            float x0 = q0.x, y0 = q0.y, x1 = q0.z, y1 = q0.w;
            float x2 = q1.x, y2 = q1.y, as = q1.w;
            // recompute winner bary exactly as reference phase-2 (same exprs)
            float w0 = (px - x1) * (y2 - y1) - (py - y1) * (x2 - x1);
            float w1 = (px - x2) * (y0 - y2) - (py - y2) * (x0 - x2);
            float w2 = (px - x0) * (y1 - y0) - (py - y0) * (x1 - x0);
            float c0 = w0 / as, c1 = w1 / as, c2 = w2 / as;
            auto segd = [&](float ax, float ay, float bx, float by) -> float {
                float dx = bx - ax, dy = by - ay;
                float l2 = dx * dx + dy * dy;
                l2 = (l2 > 1e-12f) ? l2 : 1e-12f;
                float q = ((px - ax) * dx + (py - ay) * dy) / l2;
                q = (q < 0.0f) ? 0.0f : ((q > 1.0f) ? 1.0f : q);
                float ex = (ax + q * dx) - px;
                float ey = (ay + q * dy) - py;
                return ex * ex + ey * ey;
            };
            float d2 = fminf(fminf(segd(x0, y0, x1, y1), segd(x1, y1, x2, y2)),
                             segd(x2, y2, x0, y0));
            bool inside_b = (c0 >= 0.0f) && (c1 >= 0.0f) && (c2 >= 0.0f);
            o_idx = (float)f;
            o_z = __uint_as_float((unsigned)(best >> 32));  // winner zp bits, == zbest
            ob0 = c0; ob1 = c1; ob2 = c2;
            o_d = inside_b ? -d2 : d2;
        }
        out[p] = o_idx;
        out[HWB + p] = o_z;
        out[2 * HWB + p * 3 + 0] = ob0;
        out[2 * HWB + p * 3 + 1] = ob1;
        out[2 * HWB + p * 3 + 2] = ob2;
        out[5 * HWB + p] = o_d;
    }
}

extern "C" void kernel_launch(void* const* d_in, const int* in_sizes, int n_in,
                              void* d_out, int out_size, void* d_ws, size_t ws_size,
                              hipStream_t stream) {
    const float* verts = (const float*)d_in[0];
    const float* R     = (const float*)d_in[1];
    const float* T     = (const float*)d_in[2];
    const float* focal = (const float*)d_in[3];
    const int*   faces = (const int*)d_in[4];
    float* out = (float*)d_out;
    float4* recXY = (float4*)d_ws;                       // B*F*2 float4 = 96000 B
    float4* recZ  = recXY + (size_t)Bn * Fn * 2;         // B*F   float4 = 48000 B

    hipLaunchKernelGGL(prep_kernel, dim3((Bn * Fn + 255) / 256), dim3(256), 0, stream,
                       verts, R, T, focal, faces, recXY, recZ);
    hipLaunchKernelGGL(raster_kernel, dim3(Bn * 256), dim3(1024), 0, stream,
                       recXY, recZ, out);
}